// Round 10
// baseline (99.427 us; speedup 1.0000x reference)
//
#include <hip/hip_runtime.h>

// Problem constants (fixed by the reference)
#define NB    8
#define NPTS  4096
#define KNN   16
#define HCAP  192         // halo cap: Poisson(88.5) + 11 sigma
#define QCAP  128         // query cap: Poisson(64) + 8 sigma
#define PCAP  24          // passers per query (avg 1.4; verified never hit)

// r^2 exactly as the reference: RADIUS = 5.0/480 in f64, squared in f64,
// rounded to f32 by weak promotion in `d2 < radius*radius`.
#define R2F ((float)((5.0 / 480.0) * (5.0 / 480.0)))
// Halo half-width: max true pass distance sqrt(R2F + 5e-7) ~= 0.010441;
// 0.011 leaves 5.6e-4 margin >> any fp slop in the bbox math.
#define WIN 0.011f

// ---------------------------------------------------------------------------
// K_all: ONE kernel, tile-partitioned. R9 accounting: k_all ~= 31.8us of
// which ~11us was the per-block CSR build (8192 LDS atomics + 48KB scatter
// + wave0-only prefix + 4 barriers, x512 redundant blocks). Fix: each block
// owns one spatial TILE (8x8 per batch, 512 blocks = 64 tiles x 8 batches).
//   gather: one pass over the batch's 4096 points (bbox test vs tile+halo);
//           ~88 halo points + ~64 tile queries appended to small LDS lists
//           via ~150 LDS atomics (order scrambled -> harmless, sorted later).
//   scan:   wave q handles queries j = q, q+16, ...; 64 lanes sweep the
//           ~88-entry halo list; pass = (sqn+cs2)-(tt+tt) < R2F with
//           tt = fmaf(yn,cy2,xn*cx2)  [bit-exact ref chain, verified R0-R9];
//           passers appended per-query via pcnt atomics.
//   sort:   t<nq insertion-sorts ascending, first-16, self-pad (query is
//           always in its own halo and always passes: |d_self| < 5e-7).
//   MLP:    two 64-query chunks (chunk B only if nq>64): ph3 gather+emb,
//           ph4 hidden (k-ascending fmaf, ref order), ph5 out (u-ascending,
//           b2-seeded, ref order). Layouts embT[k][lane]/hsT[u][lane]
//           conflict-free; W1/W2 rows via wave-uniform scalar loads.
// Block = 1024 thr = 16 waves; grid 512; LDS ~54KB -> 2 blocks/CU.
// ---------------------------------------------------------------------------
__global__ __launch_bounds__(1024, 8) void k_all(
    const float4* __restrict__ xytp4, const float* __restrict__ W1,
    const float* __restrict__ b1, const float* __restrict__ W2,
    const float* __restrict__ b2, float* __restrict__ out) {
#pragma clang fp contract(off)
  __shared__ float hX[HCAP], hY[HCAP], hSQ[HCAP];
  __shared__ unsigned short hIdx[HCAP];
  __shared__ float qX[QCAP], qY[QCAP];
  __shared__ unsigned short qIdx[QCAP];
  __shared__ int nH, nQ;
  __shared__ unsigned short plist[QCAP * PCAP];
  __shared__ int pcnt[QCAP];
  __shared__ unsigned short idxlsT[KNN][QCAP];  // [slot][query]
  __shared__ float embT[32][64];                // [k][lane]
  __shared__ float hsT[128][64];                // [u][lane]

  const int t = threadIdx.x;
  const int p = t & 63;                       // lane
  const int q = t >> 6;                       // wave id 0..15, uniform
  const int blk = blockIdx.x;                 // 0..511
  const int b = blk >> 6;                     // batch
  const int tile = blk & 63;
  const int tix = tile & 7, tiy = tile >> 3;
  const int bb = b << 12;                     // batch point base (global)

  const float hx0 = tix * 0.125f - WIN, hx1 = tix * 0.125f + 0.125f + WIN;
  const float hy0 = tiy * 0.125f - WIN, hy1 = tiy * 0.125f + 0.125f + WIN;

  if (t == 0) { nH = 0; nQ = 0; }
  if (t < QCAP) pcnt[t] = 0;
  __syncthreads();

  // ---- gather: one pass over the batch; append halo + query lists ----
#pragma unroll
  for (int r = 0; r < 4; ++r) {
    int i = q * 256 + r * 64 + p;             // wave-coalesced chunks
    float4 P = xytp4[bb + i];
    float x = P.y, y = P.z;
    if (x >= hx0 && x <= hx1 && y >= hy0 && y <= hy1) {
      int s = atomicAdd(&nH, 1);
      if (s < HCAP) {
        hX[s] = x; hY[s] = y;
        hSQ[s] = x * x + y * y;               // rn(rn(x^2)+rn(y^2)), as ref
        hIdx[s] = (unsigned short)i;
      }
      // tile membership: deterministic partition of [0,1)^2
      if ((int)(x * 8.0f) == tix && (int)(y * 8.0f) == tiy) {
        int sq_ = atomicAdd(&nQ, 1);
        if (sq_ < QCAP) { qX[sq_] = x; qY[sq_] = y;
                          qIdx[sq_] = (unsigned short)i; }
      }
    }
  }
  __syncthreads();

  const int nq = min(nQ, QCAP);
  const int nh = min(nH, HCAP);

  // ---- scan: wave q -> queries j = q, q+16, ...; sweep halo list ----
  for (int j = q; j < nq; j += 16) {
    float xn = qX[j], yn = qY[j];
    float sqn = xn * xn + yn * yn;            // ref sq chain (same bits)
    for (int base = 0; base < nh; base += 64) {
      int e = base + p;
      bool act = e < nh;
      int ee = act ? e : 0;
      float cx2 = hX[ee], cy2 = hY[ee], cs2 = hSQ[ee];
      float tt = fmaf(yn, cy2, xn * cx2);     // ref's contracted dot
      float d = (sqn + cs2) - (tt + tt);
      if (act && d < R2F) {
        int s = atomicAdd(&pcnt[j], 1);
        if (s < PCAP) plist[j * PCAP + s] = hIdx[ee];
      }
    }
  }
  __syncthreads();

  // ---- sort: t<nq sorts its passers ascending, first-16, self-pad ----
  if (t < nq) {
    int c = min(pcnt[t], PCAP);
    unsigned short* cand = &plist[t * PCAP];
    for (int i = 1; i < c; ++i) {             // insertion sort (c ~ 1-3)
      unsigned short key = cand[i];
      int j = i - 1;
      while (j >= 0 && cand[j] > key) { cand[j + 1] = cand[j]; --j; }
      cand[j + 1] = key;
    }
    if (c > KNN) c = KNN;
    unsigned short selfI = qIdx[t];
    for (int k = 0; k < KNN; ++k)
      idxlsT[k][t] = (k < c) ? cand[k] : selfI;
  }
  __syncthreads();

  // ---- MLP: chunks of 64 queries (chunk B only if nq > 64) ----
  const int nch = (nq > 64) ? 2 : 1;
  for (int ch = 0; ch < nch; ++ch) {
    if (ch) __syncthreads();                  // embT/hsT reuse barrier
    const int j = ch * 64 + p;
    const bool act = j < nq;
    const int jj = act ? j : 0;

    // ph3: wave q gathers neighbor slot q of its lane's query
    {
      int m = idxlsT[q][jj] & 4095;           // q uniform; safe clamp
      float4 M = xytp4[bb + m];               // L2-resident gather
      embT[2 * q][p] = qX[jj] - M.y;          // exact fp32 sub, as ref
      embT[2 * q + 1][p] = qY[jj] - M.z;      // bank p%32: conflict-free
    }
    __syncthreads();

    // ph4: wave q -> hidden units 8q..+8; k-ascending, j inner
    {
      const int u0 = __builtin_amdgcn_readfirstlane(q) * 8;
      float h[8];
#pragma unroll
      for (int x = 0; x < 8; ++x) h[x] = b1[u0 + x];
#pragma unroll
      for (int k = 0; k < 32; ++k) {          // ascending k, as ref
        float ek = embT[k][p];                // conflict-free b32
        const float* __restrict__ w0 = W1 + k * 128 + u0;  // uniform
#pragma unroll
        for (int x = 0; x < 8; ++x) h[x] = fmaf(ek, w0[x], h[x]);
      }
#pragma unroll
      for (int x = 0; x < 8; ++x)
        hsT[u0 + x][p] = fmaxf(h[x], 0.f);    // conflict-free b32 writes
    }
    __syncthreads();

    // ph5: wave q -> outputs 4q..+4; u-ascending from b2 seed
    {
      const int o0 = __builtin_amdgcn_readfirstlane(q) * 4;
      float acc[4];
#pragma unroll
      for (int x = 0; x < 4; ++x) acc[x] = b2[o0 + x];
#pragma unroll 8
      for (int g = 0; g < 64; ++g) {          // u = 2g, 2g+1, ascending
        float h0 = hsT[2 * g][p];             // ds_read2-able pair
        float h1 = hsT[2 * g + 1][p];
        const float* __restrict__ w0 = W2 + (2 * g) * 64 + o0;  // uniform
#pragma unroll
        for (int x = 0; x < 4; ++x) acc[x] = fmaf(h0, w0[x], acc[x]);
#pragma unroll
        for (int x = 0; x < 4; ++x) acc[x] = fmaf(h1, w0[64 + x], acc[x]);
      }
      if (act)
        *(float4*)(out + (size_t)(bb + qIdx[jj]) * 64 + o0) =
            make_float4(acc[0], acc[1], acc[2], acc[3]);
    }
  }
}

extern "C" void kernel_launch(void* const* d_in, const int* in_sizes, int n_in,
                              void* d_out, int out_size, void* d_ws, size_t ws_size,
                              hipStream_t stream) {
  const float4* xytp4 = (const float4*)d_in[0];  // [8,4096] (x=ch1, y=ch2)
  const float* W1 = (const float*)d_in[1];
  const float* b1 = (const float*)d_in[2];
  const float* W2 = (const float*)d_in[3];
  const float* b2 = (const float*)d_in[4];
  float* out = (float*)d_out;
  (void)d_ws; (void)ws_size;                  // workspace unused

  hipLaunchKernelGGL(k_all, dim3(512), dim3(1024), 0, stream, xytp4, W1, b1,
                     W2, b2, out);
}

// Round 12
// 86.653 us; speedup vs baseline: 1.1474x; 1.1474x over previous
//
#include <hip/hip_runtime.h>

// Problem constants (fixed by the reference)
#define NB    8
#define NPTS  4096
#define KNN   16
#define CG    16          // coarse cells per axis; cell = 0.0625
#define NCC   (CG * CG)   // 256 cells per batch
#define PCAP  24          // passer cap per query (avg ~1.4; never hit)

// r^2 exactly as the reference: RADIUS = 5.0/480 in f64, squared in f64,
// rounded to f32 by weak promotion in `d2 < radius*radius`.
#define R2F ((float)((5.0 / 480.0) * (5.0 / 480.0)))
// Window half-width for cell pruning: max true pass distance
// sqrt(R2F + 5e-7) ~= 0.010441; 0.011 leaves ample margin. 2*WIN < cell.
#define WIN 0.011f

// ---------------------------------------------------------------------------
// K_all: R9 champion structure (best measured: dur 86.25, k_all ~32us,
// every instance < 40us) + two latency/traffic cuts. R10's tile rewrite
// regressed (44.8us, VALU 30%): uniform per-block work + ordered ballot
// scan + coalesced out writes beat build-redundancy savings.
// Changes vs R9 (fp chains byte-identical, absmax must stay 0.0):
//  (1) csrSQ dropped: scan recomputes cs2 = cx*cx+cy*cy (contract off ->
//      identical rn chain, same bits). -16KB LDS, -4096 scatter stores.
//  (2) plist entries packed (idx<<12)|pos (u32): ascending u32 sort ==
//      ascending index sort (indices unique). ph3 reads neighbor coords
//      from csrX/csrY in LDS (same stored bits as xytp4 reload) -- kills
//      the dependent global gather. Self-pad = query's own CSR pos (self
//      always passes: |d_self| < 1e-6 << R2F; c>16 -> no pads needed).
//  (3) hsT overlays csrX/csrY (dead after ph3). LDS ~58KB -> 2 blocks/CU
//      = 32 waves/CU (full wave occupancy).
// Phases: build(count->prefix->scatter) / scan(ballot ordered append) /
// sort(first-16 ascending, self-pad) / ph3 emb / ph4 hidden / ph5 out.
// (R11 bench was an infra double-failure with no kernel signal; source
// unchanged — R2->R3 precedent: identical resubmit then passed.)
// ---------------------------------------------------------------------------
__global__ __launch_bounds__(1024, 8) void k_all(
    const float4* __restrict__ xytp4, const float* __restrict__ W1,
    const float* __restrict__ b1, const float* __restrict__ W2,
    const float* __restrict__ b2, float* __restrict__ out) {
#pragma clang fp contract(off)
  // Region A (32KB): csrX[4096] + csrY[4096]  ->  hsT[128][64] after ph3.
  __shared__ __align__(16) char smemA[32768];
  __shared__ unsigned short csrIdx[4096];     // point index per CSR slot
  __shared__ int offs[NCC + 1];               // CSR starts (exclusive scan)
  __shared__ int cellcnt[NCC];                // counts, then scatter cursor
  __shared__ unsigned int plist[64 * PCAP];   // packed (idx<<12)|pos
  __shared__ int pcnt[64];
  __shared__ unsigned short idxposT[KNN][64]; // [slot][query] -> CSR pos
  __shared__ float embT[32][64];              // [k][query]

  float* csrX = (float*)smemA;                      // [4096]
  float* csrY = (float*)(smemA + 16384);            // [4096]
  float(*hsT)[64] = (float(*)[64])smemA;            // 128 x 64 (after ph3)

  const int t = threadIdx.x;
  const int p = t & 63;                       // lane
  const int q = t >> 6;                       // wave id 0..15, uniform
  const int pbase = blockIdx.x * 64;          // global query base
  const int bb = pbase & ~4095;               // batch point base (global)
  const int lqbase = pbase & 4095;            // batch-local query base

  // ---- build 1: load batch points into registers, count cells ----
  float4 Preg[4];
  int cellreg[4];
#pragma unroll
  for (int r = 0; r < 4; ++r) Preg[r] = xytp4[bb + t + 1024 * r];
  if (t < NCC) cellcnt[t] = 0;
  __syncthreads();
#pragma unroll
  for (int r = 0; r < 4; ++r) {
    int cx = min(CG - 1, max(0, (int)(Preg[r].y * (float)CG)));
    int cy = min(CG - 1, max(0, (int)(Preg[r].z * (float)CG)));
    cellreg[r] = cy * CG + cx;
    atomicAdd(&cellcnt[cellreg[r]], 1);
  }
  __syncthreads();

  // ---- build 2: wave 0 exclusive-scans 256 counts (4 cells/lane) ----
  if (q == 0) {
    int b4 = p * 4;
    int s0 = cellcnt[b4], s1 = cellcnt[b4 + 1], s2 = cellcnt[b4 + 2],
        s3 = cellcnt[b4 + 3];
    int tot = s0 + s1 + s2 + s3;
    int inc = tot;
#pragma unroll
    for (int d = 1; d < 64; d <<= 1) {
      int up = __shfl_up(inc, d);
      if (p >= d) inc += up;
    }
    int ex = inc - tot;
    offs[b4] = ex; offs[b4 + 1] = ex + s0;
    offs[b4 + 2] = ex + s0 + s1; offs[b4 + 3] = ex + s0 + s1 + s2;
    if (p == 63) offs[NCC] = inc;
    cellcnt[b4] = ex; cellcnt[b4 + 1] = ex + s0;        // -> cursors
    cellcnt[b4 + 2] = ex + s0 + s1; cellcnt[b4 + 3] = ex + s0 + s1 + s2;
  }
  __syncthreads();

  // ---- build 3: scatter (x, y, idx) into CSR (order scrambled) ----
#pragma unroll
  for (int r = 0; r < 4; ++r) {
    int pos = atomicAdd(&cellcnt[cellreg[r]], 1);
    csrX[pos] = Preg[r].y; csrY[pos] = Preg[r].z;
    csrIdx[pos] = (unsigned short)(t + 1024 * r);
  }
  __syncthreads();

  // ---- scan: wave q, queries 4q..4q+3; <=2x2 cell window each ----
  {
    const int q0 = q * 4;
    const unsigned long long below = (1ull << p) - 1;
#pragma unroll
    for (int g = 0; g < 4; ++g) {
      int lq = q0 + g;
      float4 P = xytp4[pbase + lq];           // uniform addr -> broadcast
      float xn = P.y, yn = P.z;
      float sqn = xn * xn + yn * yn;          // ref sq chain
      int cxlo = max(0, (int)((xn - WIN) * (float)CG));
      int cxhi = min(CG - 1, (int)((xn + WIN) * (float)CG));
      int cylo = max(0, (int)((yn - WIN) * (float)CG));
      int cyhi = min(CG - 1, (int)((yn + WIN) * (float)CG));
      int cnt = 0;
      for (int cy_ = cylo; cy_ <= cyhi; ++cy_)
        for (int cx_ = cxlo; cx_ <= cxhi; ++cx_) {
          int cell = cy_ * CG + cx_;
          int st = offs[cell], en = offs[cell + 1];
          for (int base = st; base < en; base += 64) {
            int e = base + p;
            bool act = e < en;
            int ee = act ? e : st;            // clamp to a valid address
            float cx2 = csrX[ee], cy2 = csrY[ee];
            float cs2 = cx2 * cx2 + cy2 * cy2;    // == dropped csrSQ bits
            float tt = fmaf(yn, cy2, xn * cx2);   // ref contracted dot
            float d = (sqn + cs2) - (tt + tt);
            bool pass = act && (d < R2F);
            unsigned long long mask = __ballot(pass);
            if (pass) {
              int slot = cnt + __popcll(mask & below);
              if (slot < PCAP)
                plist[lq * PCAP + slot] =
                    ((unsigned int)csrIdx[ee] << 12) | (unsigned int)ee;
            }
            cnt += __popcll(mask);
          }
        }
      if (p == 0) pcnt[lq] = cnt;
    }
  }
  __syncthreads();

  // ---- sort: t<64 sorts packed passers ascending (== by index),
  //      first-16, self-pad with own CSR pos ----
  if (t < 64) {
    int c = min(pcnt[t], PCAP);
    unsigned int* cand = &plist[t * PCAP];
    for (int i = 1; i < c; ++i) {             // insertion sort (c ~ 1-3)
      unsigned int key = cand[i];
      int j = i - 1;
      while (j >= 0 && cand[j] > key) { cand[j + 1] = cand[j]; --j; }
      cand[j + 1] = key;
    }
    unsigned short selfPos = 0;
    if (c < KNN) {                            // self always passes -> found
      unsigned int selfIdx = (unsigned int)(lqbase + t);
      for (int i = 0; i < c; ++i)
        if ((cand[i] >> 12) == selfIdx) { selfPos = cand[i] & 4095u; break; }
    }
    if (c > KNN) c = KNN;
    for (int k = 0; k < KNN; ++k)
      idxposT[k][t] =
          (k < c) ? (unsigned short)(cand[k] & 4095u) : selfPos;
  }
  __syncthreads();

  // ---- ph3: emb from LDS CSR (wave q = slot q of every query) ----
  {
    float4 Pq = xytp4[pbase + p];             // query p's raw coords
    int m = idxposT[q][p];                    // CSR pos, q uniform
    embT[2 * q][p] = Pq.y - csrX[m];          // exact fp32 sub, same bits
    embT[2 * q + 1][p] = Pq.z - csrY[m];      // bank p%32: conflict-free
  }
  __syncthreads();                            // csrX/csrY dead after here

  // ---- ph4: wave q -> hidden units 8q..+8; k-ascending, j inner ----
  {
    const int u0 = __builtin_amdgcn_readfirstlane(q) * 8;
    float h[8];
#pragma unroll
    for (int j = 0; j < 8; ++j) h[j] = b1[u0 + j];
#pragma unroll
    for (int k = 0; k < 32; ++k) {            // ascending k, as ref
      float ek = embT[k][p];                  // conflict-free b32
      const float* __restrict__ w0 = W1 + k * 128 + u0;  // uniform
#pragma unroll
      for (int j = 0; j < 8; ++j) h[j] = fmaf(ek, w0[j], h[j]);
    }
#pragma unroll
    for (int j = 0; j < 8; ++j)
      hsT[u0 + j][p] = fmaxf(h[j], 0.f);      // overlays dead CSR region
  }
  __syncthreads();

  // ---- ph5: wave q -> outputs 4q..+4; u-ascending from b2 seed ----
  {
    const int o0 = __builtin_amdgcn_readfirstlane(q) * 4;
    float acc[4];
#pragma unroll
    for (int j = 0; j < 4; ++j) acc[j] = b2[o0 + j];
#pragma unroll 8
    for (int g = 0; g < 64; ++g) {            // u = 2g, 2g+1, ascending
      float h0 = hsT[2 * g][p];               // ds_read2-able pair
      float h1 = hsT[2 * g + 1][p];
      const float* __restrict__ w0 = W2 + (2 * g) * 64 + o0;   // uniform
#pragma unroll
      for (int j = 0; j < 4; ++j) acc[j] = fmaf(h0, w0[j], acc[j]);
#pragma unroll
      for (int j = 0; j < 4; ++j) acc[j] = fmaf(h1, w0[64 + j], acc[j]);
    }
    *(float4*)(out + (size_t)(pbase + p) * 64 + o0) =
        make_float4(acc[0], acc[1], acc[2], acc[3]);
  }
}

extern "C" void kernel_launch(void* const* d_in, const int* in_sizes, int n_in,
                              void* d_out, int out_size, void* d_ws, size_t ws_size,
                              hipStream_t stream) {
  const float4* xytp4 = (const float4*)d_in[0];  // [8,4096] (x=ch1, y=ch2)
  const float* W1 = (const float*)d_in[1];
  const float* b1 = (const float*)d_in[2];
  const float* W2 = (const float*)d_in[3];
  const float* b2 = (const float*)d_in[4];
  float* out = (float*)d_out;
  (void)d_ws; (void)ws_size;                  // workspace unused

  hipLaunchKernelGGL(k_all, dim3(512), dim3(1024), 0, stream, xytp4, W1, b1,
                     W2, b2, out);
}